// Round 1
// baseline (105.015 us; speedup 1.0000x reference)
//
#include <hip/hip_runtime.h>

#define NB 4
#define NP 8
#define NV 2048
#define NE 2048
#define NF 4096
#define BIGV 1.0e10f

// K1: blocks [0,256): chamfer min-search, 32 (b,p) combos x 8 edge-chunks.
//     blocks [256,320): volume face sums, 4 b x 16 face-chunks.
__global__ __launch_bounds__(256) void fused_k1(
    const float* __restrict__ xs, const float* __restrict__ pm,
    const float* __restrict__ edgemaps, const int* __restrict__ elen,
    const int* __restrict__ faces, unsigned* __restrict__ minbits,
    float* __restrict__ volsum)
{
    __shared__ float4 eds[256];
    __shared__ float red[4];
    const int tid = threadIdx.x;
    const int bid = blockIdx.x;

    if (bid < 256) {
        const int combo  = bid >> 3;   // b*8 + p
        const int echunk = bid & 7;
        const int b = combo >> 3;
        const int p = combo & 7;

        // Stage this block's 256-edge chunk into LDS with validity masking.
        const int e   = (echunk << 8) + tid;
        const int len = elen[combo];
        float ex = edgemaps[((size_t)combo * NE + e) * 2 + 0];
        float ey = edgemaps[((size_t)combo * NE + e) * 2 + 1];
        float e2;
        if (e < len) {
            e2 = ex * ex + ey * ey;
        } else {
            ex = 0.0f; ey = 0.0f; e2 = BIGV;   // matches ref: d2 -> BIG for invalid e
        }
        eds[tid] = make_float4(ex, ey, e2, 0.0f);

        // Projection matrix for this p (uniform -> scalar loads).
        const float* M = pm + p * 12;
        const float m00 = M[0], m01 = M[1], m02 = M[2],  m03 = M[3];
        const float m10 = M[4], m11 = M[5], m12 = M[6],  m13 = M[7];
        const float m20 = M[8], m21 = M[9], m22 = M[10], m23 = M[11];

        // Each thread owns 8 vertices (v = tid + i*256): project once.
        float px2[8], py2[8], v2[8], mn[8];
        #pragma unroll
        for (int i = 0; i < 8; i++) {
            const int v = tid + (i << 8);
            const float x = xs[((size_t)b * NV + v) * 3 + 0];
            const float y = xs[((size_t)b * NV + v) * 3 + 1];
            const float z = xs[((size_t)b * NV + v) * 3 + 2];
            const float r0 = m00 * x + m01 * y + m02 * z + m03;
            const float r1 = m10 * x + m11 * y + m12 * z + m13;
            const float r2 = m20 * x + m21 * y + m22 * z + m23;
            const float inv = 1.0f / r2;       // r2 ~ 2.0 by construction
            const float px = r0 * inv;
            const float py = r1 * inv;
            px2[i] = -2.0f * px;
            py2[i] = -2.0f * py;
            v2[i]  = px * px + py * py;        // folded out of the min, added back at end
            mn[i]  = 3.0e38f;
        }
        __syncthreads();

        // Hot loop: 256 edges x 8 vertices, 3 VALU/pair (2 fma + min).
        #pragma unroll 4
        for (int k = 0; k < 256; k++) {
            const float4 ed = eds[k];
            #pragma unroll
            for (int i = 0; i < 8; i++)
                mn[i] = fminf(mn[i], fmaf(py2[i], ed.y, fmaf(px2[i], ed.x, ed.z)));
        }

        // Merge chunk-mins across the 8 E-chunk blocks. d2 >= 0 after clamp, so
        // float bits are monotone under unsigned compare.
        #pragma unroll
        for (int i = 0; i < 8; i++) {
            const int v = tid + (i << 8);
            const float val = fmaxf(mn[i] + v2[i], 0.0f);
            atomicMin(&minbits[(size_t)combo * NV + v], __float_as_uint(val));
        }
    } else {
        // Volume: one face per thread.
        const int j = bid - 256;           // 0..63
        const int b = j >> 4;
        const int f = ((j & 15) << 8) + tid;
        const int* fc = faces + ((size_t)b * NF + f) * 3;
        const int i0 = fc[0], i1 = fc[1], i2 = fc[2];
        const float* xb = xs + (size_t)b * NV * 3;
        const float ax = xb[i0 * 3 + 0], ay = xb[i0 * 3 + 1], az = xb[i0 * 3 + 2];
        const float bx = xb[i1 * 3 + 0], by = xb[i1 * 3 + 1], bz = xb[i1 * 3 + 2];
        const float cx = xb[i2 * 3 + 0], cy = xb[i2 * 3 + 1], cz = xb[i2 * 3 + 2];
        const float crx = ay * bz - az * by;
        const float cry = az * bx - ax * bz;
        const float crz = ax * by - ay * bx;
        float fv = (crx * cx + cry * cy + crz * cz) * (1.0f / 6.0f);

        #pragma unroll
        for (int off = 32; off > 0; off >>= 1) fv += __shfl_down(fv, off);
        const int lane = tid & 63, w = tid >> 6;
        if (lane == 0) red[w] = fv;
        __syncthreads();
        if (tid == 0) atomicAdd(&volsum[b], red[0] + red[1] + red[2] + red[3]);
    }
}

// K2: one block per b. Masked mean over v per p, mean over p; volume finalize.
__global__ __launch_bounds__(256) void fused_k2(
    const unsigned* __restrict__ minbits, const void* __restrict__ maskp,
    const float* __restrict__ volsum, const float* __restrict__ tv,
    float* __restrict__ out)
{
    __shared__ float reds[4], redc[4];
    const int tid = threadIdx.x;
    const int b = blockIdx.x;

    // Sniff boundary_mask dtype: int32 0/1 words are <=1; packed 1-byte bools
    // read as words are >1 with overwhelming probability over 16 words.
    const int* mi = (const int*)maskp;
    const unsigned char* mb = (const unsigned char*)maskp;
    bool as_int = true;
    #pragma unroll
    for (int k = 0; k < 16; k++)
        if (((const unsigned*)maskp)[k] > 1u) as_int = false;

    float accum = 0.0f;
    for (int p = 0; p < NP; p++) {
        const size_t base = (size_t)(b * NP + p) * NV;
        float s = 0.0f, c = 0.0f;
        #pragma unroll
        for (int i = 0; i < 8; i++) {
            const int v = tid + (i << 8);
            const float mval = __uint_as_float(minbits[base + v]);
            const float m = as_int ? (mi[base + v] ? 1.0f : 0.0f)
                                   : (mb[base + v] ? 1.0f : 0.0f);
            s += mval * m;
            c += m;
        }
        #pragma unroll
        for (int off = 32; off > 0; off >>= 1) {
            s += __shfl_down(s, off);
            c += __shfl_down(c, off);
        }
        const int lane = tid & 63, w = tid >> 6;
        if (lane == 0) { reds[w] = s; redc[w] = c; }
        __syncthreads();
        if (tid == 0) {
            const float S = reds[0] + reds[1] + reds[2] + reds[3];
            const float C = redc[0] + redc[1] + redc[2] + redc[3];
            accum += S / fmaxf(C, 1.0f);
        }
        __syncthreads();
    }
    if (tid == 0) {
        out[b] = accum * (1.0f / NP);
        const float d = fabsf(volsum[b]) - tv[b];
        out[4 + b] = d * d;
    }
}

extern "C" void kernel_launch(void* const* d_in, const int* in_sizes, int n_in,
                              void* d_out, int out_size, void* d_ws, size_t ws_size,
                              hipStream_t stream)
{
    const float* xs       = (const float*)d_in[0];
    const float* pm       = (const float*)d_in[1];
    const float* edgemaps = (const float*)d_in[2];
    const int*   elen     = (const int*)d_in[3];
    const void*  mask     = d_in[4];
    const int*   faces    = (const int*)d_in[5];
    const float* tv       = (const float*)d_in[6];
    float* out = (float*)d_out;

    unsigned* minbits = (unsigned*)d_ws;                               // B*P*V uints = 256 KiB
    float* volsum = (float*)((char*)d_ws + (size_t)NB * NP * NV * 4);  // 4 floats

    hipMemsetAsync(minbits, 0xFF, (size_t)NB * NP * NV * 4, stream);   // uint-max = atomicMin identity
    hipMemsetAsync(volsum, 0, NB * sizeof(float), stream);

    fused_k1<<<dim3(320), dim3(256), 0, stream>>>(xs, pm, edgemaps, elen, faces, minbits, volsum);
    fused_k2<<<dim3(NB), dim3(256), 0, stream>>>(minbits, mask, volsum, tv, out);
}